// Round 2
// baseline (66.873 us; speedup 1.0000x reference)
//
#include <hip/hip_runtime.h>

// NbitTreeDecoder: static-shape tree decode (K=4 children, 8-bit flags, depth 10).
// One thread per LEAF (2^20 threads, 4096 blocks x 256) -> 16384 waves for
// latency hiding (was 4096). Within a 64-lane wave, q = leaf>>2 spans only 16
// values, so levels 0..6 are fully wave-uniform (scalar pipe) and level 7's
// flag is scalar-loaded. Output staged via LDS: stride-3 float writes (2-way
// bank alias = free) + contiguous float4 readback.

__device__ __forceinline__ unsigned sel_bit(unsigned f, unsigned d) {
    // position of d-th set bit of f (d in 0..3)
    if (d > 0u) f &= f - 1u;
    if (d > 1u) f &= f - 1u;
    if (d > 2u) f &= f - 1u;
    return (unsigned)__builtin_ctz(f);
}

__global__ __launch_bounds__(256) void nbit_tree_decode(
    const int* __restrict__ flags,
    const float* __restrict__ off3,
    const float* __restrict__ scl3,
    float* __restrict__ out)
{
    // level offsets (4^t - 1) / 3 for t = 0..9
    constexpr unsigned LOFF[10] = {0u, 1u, 5u, 21u, 85u, 341u, 1365u, 5461u, 21845u, 87381u};

    const unsigned tid = threadIdx.x;
    const unsigned g   = blockIdx.x * 256u + tid;  // leaf index, < 2^20
    const unsigned q   = g >> 2;                   // level-9 node index
    const unsigned dl  = g & 3u;                   // leaf rank within node

    // ---- levels 0..6: node index AND digit wave-uniform -> scalar pipe ----
    const unsigned qw = __builtin_amdgcn_readfirstlane(q);
    unsigned Xs = 0u;  // 21-bit scalar prefix
#pragma unroll
    for (int t = 0; t < 7; ++t) {
        const unsigned i = qw >> (18 - 2 * t);
        const unsigned d = (qw >> (16 - 2 * t)) & 3u;
        const unsigned f = (unsigned)flags[LOFF[t] + i];
        Xs = (Xs << 3) | sel_bit(f, d);
    }

    // ---- level 7: flag wave-uniform (scalar load), digit per-lane ----
    const unsigned f7 = (unsigned)flags[LOFF[7] + (qw >> 4)];
    unsigned X = (Xs << 3) | sel_bit(f7, (q >> 2) & 3u);

    // ---- level 8: 4 distinct flags per wave (L1 broadcast) ----
    const unsigned f8 = (unsigned)flags[LOFF[8] + (q >> 2)];
    X = (X << 3) | sel_bit(f8, q & 3u);

    // ---- level 9: 16 distinct flags per wave; leaf digit = dl-th set bit ----
    const unsigned f9 = (unsigned)flags[LOFF[9] + q];
    X = (X << 3) | sel_bit(f9, dl);

    const unsigned Xr = __brev(X) >> 2;  // 30-bit reversal (PERMUTE)

    const float s0 = scl3[0], s1 = scl3[1], s2 = scl3[2];
    const float o0 = off3[0], o1 = off3[1], o2 = off3[2];

    // ---- LDS stage: block image is 768 floats (192 float4), globally
    // contiguous. Stride-3 float writes: lanes i and i+32 share a bank
    // (2-way, free); readback is the standard consecutive-float4 pattern. ----
    __shared__ __align__(16) float stage[768];
    stage[3u * tid + 0u] = fmaf((float)(Xr & 1023u),         s0, o0);
    stage[3u * tid + 1u] = fmaf((float)((Xr >> 10) & 1023u), s1, o1);
    stage[3u * tid + 2u] = fmaf((float)((Xr >> 20) & 1023u), s2, o2);
    __syncthreads();

    if (tid < 192u) {
        float4* og = (float4*)out + (size_t)blockIdx.x * 192u;
        og[tid] = ((const float4*)stage)[tid];
    }
}

extern "C" void kernel_launch(void* const* d_in, const int* in_sizes, int n_in,
                              void* d_out, int out_size, void* d_ws, size_t ws_size,
                              hipStream_t stream) {
    const int*   flags  = (const int*)d_in[0];
    const float* offset = (const float*)d_in[1];
    const float* scale  = (const float*)d_in[2];
    float*       out    = (float*)d_out;

    nbit_tree_decode<<<dim3(4096), dim3(256), 0, stream>>>(flags, offset, scale, out);
}

// Round 3
// 63.678 us; speedup vs baseline: 1.0502x; 1.0502x over previous
//
#include <hip/hip_runtime.h>

// NbitTreeDecoder: static tree decode (K=4, 8-bit flags, depth 10).
// One thread per level-9 node PAIR (2^17 threads, 512 blocks x 256).
// Nodes 2u,2u+1 share digit levels 0..7 and the level-8 flag, so the
// shared prefix is decoded once per thread (8 leaves per thread).
// Levels 0..4 wave-uniform (scalar pipe); level-5 flag scalar-loaded.
// Incremental bit-reversal: for leaf digit j, only the top output field
// changes (by rev3(j)*128), so x0/x1 fma is hoisted per node.
// Output staged through XOR-swizzled LDS -> contiguous float4 stores.

__device__ __forceinline__ unsigned sel_bit(unsigned f, unsigned d) {
    // position of d-th set bit of f (d in 0..3)
    if (d > 0u) f &= f - 1u;
    if (d > 1u) f &= f - 1u;
    if (d > 2u) f &= f - 1u;
    return (unsigned)__builtin_ctz(f);
}

__device__ __forceinline__ unsigned swz(unsigned s) {  // bijective per 64-slot block
    return s ^ ((s >> 3) & 7u);
}

__global__ __launch_bounds__(256) void nbit_tree_decode(
    const int* __restrict__ flags,
    const float* __restrict__ off3,
    const float* __restrict__ scl3,
    float* __restrict__ out)
{
    // level offsets (4^t - 1) / 3 for t = 0..9
    constexpr unsigned LOFF[10] = {0u, 1u, 5u, 21u, 85u, 341u, 1365u, 5461u, 21845u, 87381u};

    const unsigned tid = threadIdx.x;
    const unsigned u   = blockIdx.x * 256u + tid;   // node-pair index, < 2^17
    // q0 = 2u, q1 = 2u+1 are the two level-9 nodes owned by this thread.

    // ---- levels 0..4: node index AND digit wave-uniform -> scalar pipe ----
    const unsigned uw = __builtin_amdgcn_readfirstlane(u);
    unsigned P = 0u;  // shared digit prefix (levels 0..7), 24 bits when done
#pragma unroll
    for (int t = 0; t < 5; ++t) {
        const unsigned i = uw >> (17 - 2 * t);          // q >> (18-2t)
        const unsigned d = (uw >> (15 - 2 * t)) & 3u;   // (q >> (16-2t)) & 3
        const unsigned f = (unsigned)flags[LOFF[t] + i];
        P = (P << 3) | sel_bit(f, d);
    }
    // ---- level 5: flag wave-uniform (scalar load), digit per-lane (2 values) ----
    {
        const unsigned f5 = (unsigned)flags[LOFF[5] + (uw >> 7)];
        P = (P << 3) | sel_bit(f5, (u >> 5) & 3u);
    }
    // ---- levels 6,7: per-lane (2 / 8 distinct flags per wave, L1 broadcast) ----
    {
        const unsigned f6 = (unsigned)flags[LOFF[6] + (u >> 5)];
        P = (P << 3) | sel_bit(f6, (u >> 3) & 3u);
        const unsigned f7 = (unsigned)flags[LOFF[7] + (u >> 3)];
        P = (P << 3) | sel_bit(f7, (u >> 1) & 3u);
    }
    // ---- level 8: ONE flag, two digits (e and e|1) ----
    const unsigned f8   = (unsigned)flags[LOFF[8] + (u >> 1)];
    const unsigned e    = (u & 1u) << 1;
    const unsigned b8_0 = sel_bit(f8, e);
    const unsigned b8_1 = sel_bit(f8, e | 1u);

    // ---- level 9: two adjacent flags (odd base offset -> two dword loads) ----
    const unsigned f9_0 = (unsigned)flags[LOFF[9] + (u << 1)];
    const unsigned f9_1 = (unsigned)flags[LOFF[9] + (u << 1) + 1u];

    const float s0 = scl3[0], s1 = scl3[1], s2 = scl3[2];
    const float o0 = off3[0], o1 = off3[1], o2 = off3[2];
    const float s2x128 = s2 * 128.0f;   // leaf digit contributes rev3(j)<<7 to field 2

    // ---- LDS stage: block image is 1536 float4 (24 KB), globally contiguous ----
    __shared__ __align__(16) float4 stage[1536];

#pragma unroll
    for (int n = 0; n < 2; ++n) {
        const unsigned b8     = n ? b8_1 : b8_0;
        unsigned       f9     = n ? f9_1 : f9_0;
        const unsigned base27 = (P << 3) | b8;
        // Xr(j) = (brev(base27) >> 5) | (rev3(j) << 27); fields 0,1 leaf-invariant.
        const unsigned Rb = __brev(base27) >> 5;
        const float v0  = fmaf((float)(Rb & 1023u),         s0, o0);
        const float v1  = fmaf((float)((Rb >> 10) & 1023u), s1, o1);
        const float v2b = fmaf((float)(Rb >> 20),           s2, o2);
        float w[4];
#pragma unroll
        for (int d = 0; d < 4; ++d) {
            const unsigned j = (unsigned)__builtin_ctz(f9);  // ascending = child order
            f9 &= f9 - 1u;
            // rev3(j) via v_perm byte LUT: [0,4,2,6,1,5,3,7]
            const unsigned ji = __builtin_amdgcn_perm(0x07030501u, 0x06020400u, j);
            w[d] = fmaf((float)ji, s2x128, v2b);
        }
        const unsigned sb = 6u * tid + 3u * (unsigned)n;
        stage[swz(sb + 0u)] = make_float4(v0,   v1,   w[0], v0);
        stage[swz(sb + 1u)] = make_float4(v1,   w[1], v0,   v1);
        stage[swz(sb + 2u)] = make_float4(w[2], v0,   v1,   w[3]);
    }
    __syncthreads();

    float4* og = (float4*)out + (size_t)blockIdx.x * 1536u;
#pragma unroll
    for (int k = 0; k < 6; ++k) {
        const unsigned s = 256u * k + tid;
        og[s] = stage[swz(s)];   // contiguous 1024B per wave-instruction
    }
}

extern "C" void kernel_launch(void* const* d_in, const int* in_sizes, int n_in,
                              void* d_out, int out_size, void* d_ws, size_t ws_size,
                              hipStream_t stream) {
    const int*   flags  = (const int*)d_in[0];
    const float* offset = (const float*)d_in[1];
    const float* scale  = (const float*)d_in[2];
    float*       out    = (float*)d_out;

    nbit_tree_decode<<<dim3(512), dim3(256), 0, stream>>>(flags, offset, scale, out);
}

// Round 5
// 62.746 us; speedup vs baseline: 1.0658x; 1.0149x over previous
//
#include <hip/hip_runtime.h>

// NbitTreeDecoder: static-shape tree decode (K=4 children, 8-bit flags, depth 10).
// R1 structure (best measured): one thread per level-9 node (2^18 threads,
// 1024 x 256), 4 leaves per thread, levels 0..5 on the scalar pipe,
// XOR-swizzled LDS stage -> contiguous float4 stores.
// R4 polish: incremental bit-reversal (leaf digit contributes rev3(j)<<7 to
// output field 2 only; fields 0,1 hoisted per node) + nontemporal stores
// (via clang ext_vector_type -- HIP's float4 class is rejected by the builtin).

using f32x4 = __attribute__((ext_vector_type(4))) float;

__device__ __forceinline__ unsigned sel_bit(unsigned f, unsigned d) {
    // position of d-th set bit of f (d in 0..3)
    if (d > 0u) f &= f - 1u;
    if (d > 1u) f &= f - 1u;
    if (d > 2u) f &= f - 1u;
    return (unsigned)__builtin_ctz(f);
}

__device__ __forceinline__ unsigned swz(unsigned s) {  // bijective per 64-slot block
    return s ^ ((s >> 3) & 7u);
}

__global__ __launch_bounds__(256) void nbit_tree_decode(
    const int* __restrict__ flags,
    const float* __restrict__ off3,
    const float* __restrict__ scl3,
    float* __restrict__ out)
{
    // level offsets (4^t - 1) / 3 for t = 0..9
    constexpr unsigned LOFF[10] = {0u, 1u, 5u, 21u, 85u, 341u, 1365u, 5461u, 21845u, 87381u};

    const unsigned tid = threadIdx.x;
    const unsigned q = blockIdx.x * 256u + tid;   // level-9 node index, < 2^18

    // ---- levels 0..5: wave-uniform (q>>6 identical across the wave) ----
    const unsigned qw = __builtin_amdgcn_readfirstlane(q);
    unsigned Xs = 0u;  // 18-bit scalar prefix
#pragma unroll
    for (int t = 0; t < 6; ++t) {
        const unsigned i = qw >> (18 - 2 * t);
        const unsigned d = (qw >> (16 - 2 * t)) & 3u;
        const unsigned f = (unsigned)flags[LOFF[t] + i];
        Xs = (Xs << 3) | sel_bit(f, d);
    }

    // ---- levels 6..8: per-lane ----
    unsigned Xv = 0u;
#pragma unroll
    for (int t = 6; t < 9; ++t) {
        const unsigned i = q >> (18 - 2 * t);
        const unsigned d = (q >> (16 - 2 * t)) & 3u;
        const unsigned f = (unsigned)flags[LOFF[t] + i];
        Xv = (Xv << 3) | sel_bit(f, d);
    }
    const unsigned base27 = (Xs << 9) | Xv;   // 27-bit prefix

    unsigned f9 = (unsigned)flags[LOFF[9] + q];

    const float s0 = scl3[0], s1 = scl3[1], s2 = scl3[2];
    const float o0 = off3[0], o1 = off3[1], o2 = off3[2];
    const float s2x128 = s2 * 128.0f;  // leaf digit lands at bit 7 of field 2

    // Xr(j) = rev27(base27) | rev3(j)<<27; fields 0,1 are leaf-invariant.
    const unsigned Rb = __brev(base27) >> 5;               // 27-bit reversal
    const float v0  = fmaf((float)(Rb & 1023u),         s0, o0);
    const float v1  = fmaf((float)((Rb >> 10) & 1023u), s1, o1);
    const float v2b = fmaf((float)(Rb >> 20),           s2, o2);  // top 7 bits

    float w[4];
#pragma unroll
    for (int d = 0; d < 4; ++d) {
        const unsigned j = (unsigned)__builtin_ctz(f9);  // set bits ascending = child order
        f9 &= f9 - 1u;
        // rev3(j) via v_perm byte LUT: [0,4,2,6,1,5,3,7]
        const unsigned ji = __builtin_amdgcn_perm(0x07030501u, 0x06020400u, j);
        w[d] = fmaf((float)ji, s2x128, v2b);
    }

    // ---- LDS stage: block image is 768 float4 (12 KB), globally contiguous.
    // Leaf d occupies floats [12q+3d, 12q+3d+3): pack (v0,v1,w[d]) runs. ----
    __shared__ __align__(16) f32x4 stage[768];
    const unsigned sb = 3u * tid;
    stage[swz(sb + 0u)] = (f32x4){v0,   v1,   w[0], v0};
    stage[swz(sb + 1u)] = (f32x4){v1,   w[1], v0,   v1};
    stage[swz(sb + 2u)] = (f32x4){w[2], v0,   v1,   w[3]};
    __syncthreads();

    f32x4* og = (f32x4*)out + (size_t)blockIdx.x * 768u;
#pragma unroll
    for (int k = 0; k < 3; ++k) {
        const unsigned s = 256u * k + tid;
        __builtin_nontemporal_store(stage[swz(s)], og + s);  // contiguous 1024B/instr
    }
}

extern "C" void kernel_launch(void* const* d_in, const int* in_sizes, int n_in,
                              void* d_out, int out_size, void* d_ws, size_t ws_size,
                              hipStream_t stream) {
    const int*   flags  = (const int*)d_in[0];
    const float* offset = (const float*)d_in[1];
    const float* scale  = (const float*)d_in[2];
    float*       out    = (float*)d_out;

    nbit_tree_decode<<<dim3(1024), dim3(256), 0, stream>>>(flags, offset, scale, out);
}